// Round 1
// 1375.100 us; speedup vs baseline: 1.3376x; 1.3376x over previous
//
#include <hip/hip_runtime.h>
#include <cstddef>

// Problem constants (from reference):
#define L_SEQ  2048
#define B_SZ   2
#define E_DIM  1024
#define H_N    16
#define D_HEAD 64
#define R_DIM  256

typedef unsigned short u16;
using bf16x8 = __attribute__((ext_vector_type(8))) short;   // 8 bf16 (4 VGPRs) — guide §3
using f32x4  = __attribute__((ext_vector_type(4))) float;   // MFMA accumulator

// RNE fp32 -> bf16 (matches v_cvt semantics)
__device__ __forceinline__ u16 bf16rne(float f) {
    unsigned u = __float_as_uint(f);
    return (u16)((u + 0x7FFFu + ((u >> 16) & 1u)) >> 16);
}
__device__ __forceinline__ float b2f(u16 h) {
    return __uint_as_float(((unsigned)h) << 16);
}

// ---------------------------------------------------------------------------
// fp32 -> bf16 hi/lo conversion (grid-stride, float4 vectorized)
// ---------------------------------------------------------------------------
__global__ __launch_bounds__(256)
void convert_hilo(const float* __restrict__ in, u16* __restrict__ hi,
                  u16* __restrict__ lo, int n4)
{
    for (int i = blockIdx.x * 256 + threadIdx.x; i < n4; i += gridDim.x * 256) {
        float4 v = ((const float4*)in)[i];
        u16 h0 = bf16rne(v.x), h1 = bf16rne(v.y), h2 = bf16rne(v.z), h3 = bf16rne(v.w);
        uint2 hp;
        hp.x = (unsigned)h0 | ((unsigned)h1 << 16);
        hp.y = (unsigned)h2 | ((unsigned)h3 << 16);
        ((uint2*)hi)[i] = hp;
        u16 l0 = bf16rne(v.x - b2f(h0)), l1 = bf16rne(v.y - b2f(h1));
        u16 l2 = bf16rne(v.z - b2f(h2)), l3 = bf16rne(v.w - b2f(h3));
        uint2 lp;
        lp.x = (unsigned)l0 | ((unsigned)l1 << 16);
        lp.y = (unsigned)l2 | ((unsigned)l3 << 16);
        ((uint2*)lo)[i] = lp;
    }
}

// ---------------------------------------------------------------------------
// fp32 [rows][cols] -> bf16 hi/lo transposed [cols][rows]   (for U^T)
// ---------------------------------------------------------------------------
__global__ __launch_bounds__(256)
void transpose_f32_hilo(const float* __restrict__ in, u16* __restrict__ oh,
                        u16* __restrict__ ol, int rows, int cols)
{
    __shared__ float t[32][33];
    const int tx = threadIdx.x & 31, ty = threadIdx.x >> 5;
    const int r0 = blockIdx.y * 32, c0 = blockIdx.x * 32;
    #pragma unroll
    for (int i = 0; i < 4; i++)
        t[ty + i * 8][tx] = in[(size_t)(r0 + ty + i * 8) * cols + c0 + tx];
    __syncthreads();
    #pragma unroll
    for (int i = 0; i < 4; i++) {
        float v = t[tx][ty + i * 8];
        u16 h = bf16rne(v);
        size_t o = (size_t)(c0 + ty + i * 8) * rows + r0 + tx;
        oh[o] = h;
        ol[o] = bf16rne(v - b2f(h));
    }
}

// ---------------------------------------------------------------------------
// V [L,B,E] bf16 -> Vt [B*H, D, L] bf16 (per-head transpose so PV is TRANSB)
// ---------------------------------------------------------------------------
__global__ __launch_bounds__(256)
void transpose_v_bf16(const u16* __restrict__ vh, u16* __restrict__ vt)
{
    __shared__ u16 t[32][34];   // 34*2B = 68B stride: 17 words, coprime w/ 32 banks
    const int tx = threadIdx.x & 31, ty = threadIdx.x >> 5;
    const int l0 = blockIdx.x * 32, d0 = blockIdx.y * 32;
    const int z = blockIdx.z, b = z >> 4, h = z & 15;
    #pragma unroll
    for (int i = 0; i < 4; i++)
        t[ty + i * 8][tx] =
            vh[(size_t)((l0 + ty + i * 8) * B_SZ + b) * E_DIM + h * D_HEAD + d0 + tx];
    __syncthreads();
    #pragma unroll
    for (int i = 0; i < 4; i++)
        vt[(size_t)(z * D_HEAD + d0 + ty + i * 8) * L_SEQ + l0 + tx] = t[tx][ty + i * 8];
}

// ---------------------------------------------------------------------------
// MFMA GEMM:  C = alpha * A @ B^T + beta * Cin + bias
//   All B operands are [N,K] (TRANSB everywhere; U and V pre-transposed).
//   A: bf16 hi(/lo) [M,K], or fp32 (AF32) converted during staging (PV path).
//   SPLIT: 3-MFMA hi/lo emulation (~fp32 accuracy, guide-verified layouts).
//   Outputs (each optional): Cf fp32, Ch bf16-hi, Cl bf16-lo residual.
//   Offset modes: 0 -> z*stride ; 1 -> (z/H)*E + (z%H)*D  (head-sliced view)
// Tile: BM=128 x BN x BK=64, 4 waves (2x2), wave tile 64 x BN/2,
//   mfma_f32_16x16x32_bf16. LDS K-major with XOR granule swizzle (T2):
//   granule' = granule ^ (row&7) -> frag ds_read_b128 conflict-free.
// ---------------------------------------------------------------------------
template <int BN, bool SPLIT, bool AF32>
__global__ __launch_bounds__(256)
void gemm_mfma(const void* __restrict__ Ah_, const void* __restrict__ Al_,
               const u16* __restrict__ Bh_, const u16* __restrict__ Bl_,
               float* __restrict__ Cf, u16* __restrict__ Ch, u16* __restrict__ Cl,
               const u16* __restrict__ Cinh, const u16* __restrict__ Cinl,
               const float* __restrict__ bias,
               int M, int N, int K, int lda, int ldb, int ldc,
               long aStride, int aMode, long bStride, int bMode,
               long cStride, int cMode, float alpha, float beta)
{
    constexpr int BM = 128, BK = 64;
    constexpr int WN = BN / 32;                 // N-frags per wave (4 or 2)
    constexpr int ALO = BM * BK, BLO = BN * BK; // lo-buffer offsets (u16 units)
    __shared__ u16 As[(SPLIT ? 2 : 1) * BM * BK];
    __shared__ u16 Bs[(SPLIT ? 2 : 1) * BN * BK];

    const int tid = threadIdx.x;
    const int z = blockIdx.z;
    const int headOff = (z >> 4) * E_DIM + (z & 15) * D_HEAD;
    const int aOff = aMode ? headOff : (int)(z * aStride);
    const int bOff = bMode ? headOff : (int)(z * bStride);
    const int cOff = cMode ? headOff : (int)(z * cStride);
    const int tm = blockIdx.y * BM, tn = blockIdx.x * BN;

    // staging coords: thread -> (row chunk, 8-elem k-granule)
    const int sRow = tid >> 3, sG = tid & 7;
    // fragment coords
    const int lane = tid & 63;
    const int fr = lane & 15, kg = lane >> 4;
    const int wave = tid >> 6;
    const int wm = (wave >> 1) * 64;
    const int wn = (wave & 1) * (BN / 2);

    f32x4 acc[4][WN] = {};

    for (int k0 = 0; k0 < K; k0 += BK) {
        // ---- stage A panel ----
        if constexpr (!AF32) {
            const u16* Ah = (const u16*)Ah_ + aOff + k0;
            #pragma unroll
            for (int i = 0; i < 4; i++) {
                int row = sRow + i * 32;
                int p = sG ^ (row & 7);
                int dst = row * BK + p * 8;
                *(uint4*)&As[dst] = *(const uint4*)(Ah + (tm + row) * lda + sG * 8);
                if constexpr (SPLIT) {
                    const u16* Al = (const u16*)Al_ + aOff + k0;
                    *(uint4*)&As[ALO + dst] = *(const uint4*)(Al + (tm + row) * lda + sG * 8);
                }
            }
        } else {
            // fp32 A (attn matrix): convert to bf16 during staging
            const float* Af = (const float*)Ah_ + aOff + k0;
            const int rowF = tid >> 4, qF = tid & 15;
            #pragma unroll
            for (int i = 0; i < 8; i++) {
                int row = rowF + i * 16;
                float4 v = *(const float4*)(Af + (tm + row) * lda + qF * 4);
                int p = (qF >> 1) ^ (row & 7);
                uint2 pk;
                pk.x = (unsigned)bf16rne(v.x) | ((unsigned)bf16rne(v.y) << 16);
                pk.y = (unsigned)bf16rne(v.z) | ((unsigned)bf16rne(v.w) << 16);
                *(uint2*)&As[row * BK + p * 8 + (qF & 1) * 4] = pk;
            }
        }
        // ---- stage B panel ([N,K] rows) ----
        {
            const u16* Bh = Bh_ + bOff + k0;
            #pragma unroll
            for (int i = 0; i < BN / 32; i++) {
                int row = sRow + i * 32;
                int p = sG ^ (row & 7);
                int dst = row * BK + p * 8;
                *(uint4*)&Bs[dst] = *(const uint4*)(Bh + (tn + row) * ldb + sG * 8);
                if constexpr (SPLIT) {
                    const u16* Bl = Bl_ + bOff + k0;
                    *(uint4*)&Bs[BLO + dst] = *(const uint4*)(Bl + (tn + row) * ldb + sG * 8);
                }
            }
        }
        __syncthreads();

        // ---- compute: 2 MFMA k-steps of 32 per panel ----
        #pragma unroll
        for (int ks = 0; ks < 2; ks++) {
            bf16x8 ah[4], al[4];
            #pragma unroll
            for (int m = 0; m < 4; m++) {
                int row = wm + m * 16 + fr;
                int p = (ks * 4 + kg) ^ (row & 7);
                ah[m] = *(const bf16x8*)&As[row * BK + p * 8];
                if constexpr (SPLIT)
                    al[m] = *(const bf16x8*)&As[ALO + row * BK + p * 8];
            }
            #pragma unroll
            for (int n = 0; n < WN; n++) {
                int col = wn + n * 16 + fr;
                int p = (ks * 4 + kg) ^ (col & 7);
                bf16x8 bh = *(const bf16x8*)&Bs[col * BK + p * 8];
                #pragma unroll
                for (int m = 0; m < 4; m++)
                    acc[m][n] = __builtin_amdgcn_mfma_f32_16x16x32_bf16(ah[m], bh, acc[m][n], 0, 0, 0);
                if constexpr (SPLIT) {
                    bf16x8 bl = *(const bf16x8*)&Bs[BLO + col * BK + p * 8];
                    #pragma unroll
                    for (int m = 0; m < 4; m++) {
                        acc[m][n] = __builtin_amdgcn_mfma_f32_16x16x32_bf16(al[m], bh, acc[m][n], 0, 0, 0);
                        acc[m][n] = __builtin_amdgcn_mfma_f32_16x16x32_bf16(ah[m], bl, acc[m][n], 0, 0, 0);
                    }
                }
            }
        }
        __syncthreads();
    }

    // ---- epilogue: C/D layout col=lane&15, row=(lane>>4)*4+reg (m89-verified) ----
    #pragma unroll
    for (int m = 0; m < 4; m++) {
        int row0 = tm + wm + m * 16 + kg * 4;
        #pragma unroll
        for (int n = 0; n < WN; n++) {
            int col = tn + wn + n * 16 + fr;
            float bv = bias ? bias[col] : 0.0f;
            #pragma unroll
            for (int j = 0; j < 4; j++) {
                int idx = cOff + (row0 + j) * ldc + col;
                float v = alpha * acc[m][n][j] + bv;
                if (beta != 0.0f) {
                    float ci = b2f(Cinh[idx]);
                    if (Cinl) ci += b2f(Cinl[idx]);
                    v += beta * ci;
                }
                if (Cf) Cf[idx] = v;
                if (Ch) {
                    u16 h = bf16rne(v);
                    Ch[idx] = h;
                    if (Cl) Cl[idx] = bf16rne(v - b2f(h));
                }
            }
        }
    }
}

// ---------------------------------------------------------------------------
// Row softmax in place over the attention score matrix (unchanged, fp32).
// ---------------------------------------------------------------------------
__global__ __launch_bounds__(256)
void softmax_rows(float* __restrict__ attn, const float* __restrict__ mask)
{
    const int l  = blockIdx.x & (L_SEQ - 1);
    const int bh = blockIdx.x >> 11;
    float* row        = attn + ((size_t)bh * L_SEQ + l) * L_SEQ;
    const float* mrow = mask + (size_t)l * L_SEQ;

    const int tid  = threadIdx.x;
    const int wave = tid >> 6;
    const int lane = tid & 63;

    float v[8];
    float mx = -3.4e38f;
    #pragma unroll
    for (int i = 0; i < 8; i++) {
        const int idx = tid + i * 256;
        v[i] = row[idx] + mrow[idx];
        mx = fmaxf(mx, v[i]);
    }
    #pragma unroll
    for (int off = 32; off >= 1; off >>= 1)
        mx = fmaxf(mx, __shfl_xor(mx, off, 64));

    __shared__ float sred[4];
    if (lane == 0) sred[wave] = mx;
    __syncthreads();
    mx = fmaxf(fmaxf(sred[0], sred[1]), fmaxf(sred[2], sred[3]));

    float sum = 0.0f;
    #pragma unroll
    for (int i = 0; i < 8; i++) {
        v[i] = __expf(v[i] - mx);
        sum += v[i];
    }
    #pragma unroll
    for (int off = 32; off >= 1; off >>= 1)
        sum += __shfl_xor(sum, off, 64);

    __syncthreads();
    if (lane == 0) sred[wave] = sum;
    __syncthreads();
    const float total = sred[0] + sred[1] + sred[2] + sred[3];
    const float inv = 1.0f / total;

    #pragma unroll
    for (int i = 0; i < 8; i++)
        row[tid + i * 256] = v[i] * inv;
}

// ---------------------------------------------------------------------------
extern "C" void kernel_launch(void* const* d_in, const int* in_sizes, int n_in,
                              void* d_out, int out_size, void* d_ws, size_t ws_size,
                              hipStream_t stream)
{
    const float* x    = (const float*)d_in[0];
    const float* mask = (const float*)d_in[1];
    const float* Wq   = (const float*)d_in[2];
    const float* bq   = (const float*)d_in[3];
    const float* Wk   = (const float*)d_in[4];
    const float* bk   = (const float*)d_in[5];
    const float* Wv   = (const float*)d_in[6];
    const float* bv   = (const float*)d_in[7];
    const float* Wo   = (const float*)d_in[8];
    const float* bo   = (const float*)d_in[9];
    const float* U    = (const float*)d_in[10];

    float* out   = (float*)d_out;                               // [L,B,E]
    float* attnF = out + (size_t)L_SEQ * B_SZ * E_DIM;          // [B,H,L,L]

    const int SZ  = L_SEQ * B_SZ * E_DIM;   // 4,194,304
    const int WSZ = E_DIM * E_DIM;          // 1,048,576
    const int USZ = E_DIM * R_DIM;          //   262,144
    const int PSZ = L_SEQ * B_SZ * R_DIM;   // 1,048,576

    // ---- persistent ws (live after scores overwrite attn region): 44 MB ----
    // (previous session proved ws_size >= 54.5 MB)
    u16* Qch  = (u16*)d_ws;
    u16* Kch  = Qch + SZ;
    u16* Vth  = Kch + SZ;          // V^T per head: [B*H, D, L]
    u16* ctxh = Vth + SZ;
    u16* ctxl = ctxh + SZ;
    u16* Woh  = ctxl + SZ;
    u16* Wol  = Woh + WSZ;

    // ---- pre-scores scratch lives in the (not-yet-written) attn region ----
    u16* sc  = (u16*)attnF;
    u16* xh  = sc;          u16* xl  = xh + SZ;
    u16* Qh  = xl + SZ;     u16* Ql  = Qh + SZ;
    u16* Kh  = Ql + SZ;     u16* Kl  = Kh + SZ;
    u16* Vh  = Kl + SZ;
    u16* Wqh = Vh + SZ;     u16* Wql = Wqh + WSZ;
    u16* Wkh = Wql + WSZ;   u16* Wkl = Wkh + WSZ;
    u16* Wvh = Wkl + WSZ;   u16* Wvl = Wvh + WSZ;
    u16* Uh  = Wvl + WSZ;   u16* Ul  = Uh + USZ;
    u16* Uth = Ul + USZ;    u16* Utl = Uth + USZ;   // U^T [R,E]
    u16* Ph  = Utl + USZ;   u16* Pl  = Ph + PSZ;    // ~78 MB total << 536 MB

    const dim3 blk(256);
    const int M = L_SEQ * B_SZ;  // 4096

    // 0. fp32 -> bf16 hi/lo conversions
    hipLaunchKernelGGL(convert_hilo, dim3(2048), blk, 0, stream, x,  xh,  xl,  SZ / 4);
    hipLaunchKernelGGL(convert_hilo, dim3(512),  blk, 0, stream, Wq, Wqh, Wql, WSZ / 4);
    hipLaunchKernelGGL(convert_hilo, dim3(512),  blk, 0, stream, Wk, Wkh, Wkl, WSZ / 4);
    hipLaunchKernelGGL(convert_hilo, dim3(512),  blk, 0, stream, Wv, Wvh, Wvl, WSZ / 4);
    hipLaunchKernelGGL(convert_hilo, dim3(512),  blk, 0, stream, Wo, Woh, Wol, WSZ / 4);
    hipLaunchKernelGGL(convert_hilo, dim3(128),  blk, 0, stream, U,  Uh,  Ul,  USZ / 4);
    hipLaunchKernelGGL(transpose_f32_hilo, dim3(R_DIM / 32, E_DIM / 32), blk, 0, stream,
                       U, Uth, Utl, E_DIM, R_DIM);

    // 1-3. Q/K/V projections (split-bf16, ~fp32 accuracy): [4096,1024]
    {
        dim3 g(E_DIM / 128, M / 128, 1);
        hipLaunchKernelGGL((gemm_mfma<128, true, false>), g, blk, 0, stream,
            xh, xl, Wqh, Wql, nullptr, Qh, Ql, nullptr, nullptr, bq,
            M, E_DIM, E_DIM, E_DIM, E_DIM, E_DIM,
            0L, 0, 0L, 0, 0L, 0, 1.0f, 0.0f);
        hipLaunchKernelGGL((gemm_mfma<128, true, false>), g, blk, 0, stream,
            xh, xl, Wkh, Wkl, nullptr, Kh, Kl, nullptr, nullptr, bk,
            M, E_DIM, E_DIM, E_DIM, E_DIM, E_DIM,
            0L, 0, 0L, 0, 0L, 0, 1.0f, 0.0f);
        hipLaunchKernelGGL((gemm_mfma<128, true, false>), g, blk, 0, stream,
            xh, xl, Wvh, Wvl, nullptr, Vh, nullptr, nullptr, nullptr, bv,
            M, E_DIM, E_DIM, E_DIM, E_DIM, E_DIM,
            0L, 0, 0L, 0, 0L, 0, 1.0f, 0.0f);
    }
    hipLaunchKernelGGL(transpose_v_bf16, dim3(L_SEQ / 32, D_HEAD / 32, B_SZ * H_N),
                       blk, 0, stream, Vh, Vth);

    // 4-5. Conditioning: P = Q@U ; Qc = 0.4*P@U^T + 0.6*Q  (bf16 out for scores)
    {
        dim3 gp(R_DIM / 128, M / 128, 1);
        dim3 gc(E_DIM / 128, M / 128, 1);
        hipLaunchKernelGGL((gemm_mfma<128, true, false>), gp, blk, 0, stream,
            Qh, Ql, Uth, Utl, nullptr, Ph, Pl, nullptr, nullptr, nullptr,
            M, R_DIM, E_DIM, E_DIM, E_DIM, R_DIM,
            0L, 0, 0L, 0, 0L, 0, 1.0f, 0.0f);
        hipLaunchKernelGGL((gemm_mfma<128, true, false>), gc, blk, 0, stream,
            Ph, Pl, Uh, Ul, nullptr, Qch, nullptr, Qh, Ql, nullptr,
            M, E_DIM, R_DIM, R_DIM, R_DIM, E_DIM,
            0L, 0, 0L, 0, 0L, 0, 0.4f, 0.6f);
        hipLaunchKernelGGL((gemm_mfma<128, true, false>), gp, blk, 0, stream,
            Kh, Kl, Uth, Utl, nullptr, Ph, Pl, nullptr, nullptr, nullptr,
            M, R_DIM, E_DIM, E_DIM, E_DIM, R_DIM,
            0L, 0, 0L, 0, 0L, 0, 1.0f, 0.0f);
        hipLaunchKernelGGL((gemm_mfma<128, true, false>), gc, blk, 0, stream,
            Ph, Pl, Uh, Ul, nullptr, Kch, nullptr, Kh, Kl, nullptr,
            M, E_DIM, R_DIM, R_DIM, R_DIM, E_DIM,
            0L, 0, 0L, 0, 0L, 0, 0.4f, 0.6f);
    }

    // 7. Scores: per (b,h): attn = (q @ k^T) / 8  (plain bf16 MFMA, fp32 out)
    {
        dim3 g(L_SEQ / 128, L_SEQ / 128, B_SZ * H_N);
        hipLaunchKernelGGL((gemm_mfma<128, false, false>), g, blk, 0, stream,
            Qch, nullptr, Kch, nullptr, attnF, nullptr, nullptr, nullptr, nullptr, nullptr,
            L_SEQ, L_SEQ, D_HEAD, B_SZ * E_DIM, B_SZ * E_DIM, L_SEQ,
            0L, 1, 0L, 1, (long)L_SEQ * L_SEQ, 0, 0.125f, 0.0f);
    }

    // 8. softmax(scores + mask) in place (fp32)
    hipLaunchKernelGGL(softmax_rows, dim3(B_SZ * H_N * L_SEQ), blk, 0, stream,
                       attnF, mask);

    // 9. ctx = attn @ V   (A fp32->bf16 in staging; B = Vt TRANSB; bf16 hi/lo out)
    {
        dim3 g(1, L_SEQ / 128, B_SZ * H_N);
        hipLaunchKernelGGL((gemm_mfma<64, false, true>), g, blk, 0, stream,
            attnF, nullptr, Vth, nullptr, nullptr, ctxh, ctxl, nullptr, nullptr, nullptr,
            L_SEQ, D_HEAD, L_SEQ, L_SEQ, L_SEQ, B_SZ * E_DIM,
            (long)L_SEQ * L_SEQ, 0, (long)D_HEAD * L_SEQ, 0, 0L, 1, 1.0f, 0.0f);
    }

    // 10. out = ctx @ Wo^T + bo  (split-bf16)
    {
        dim3 g(E_DIM / 128, M / 128, 1);
        hipLaunchKernelGGL((gemm_mfma<128, true, false>), g, blk, 0, stream,
            ctxh, ctxl, Woh, Wol, out, nullptr, nullptr, nullptr, nullptr, bo,
            M, E_DIM, E_DIM, E_DIM, E_DIM, E_DIM,
            0L, 0, 0L, 0, 0L, 0, 1.0f, 0.0f);
    }
}

// Round 3
// 1084.235 us; speedup vs baseline: 1.6965x; 1.2683x over previous
//
#include <hip/hip_runtime.h>
#include <cstddef>

// Problem constants (from reference):
#define L_SEQ  2048
#define B_SZ   2
#define E_DIM  1024
#define H_N    16
#define D_HEAD 64
#define R_DIM  256

typedef unsigned short u16;
using bf16x8 = __attribute__((ext_vector_type(8))) short;   // 8 bf16 (4 VGPRs)
using f32x4  = __attribute__((ext_vector_type(4))) float;   // MFMA accumulator

// RNE fp32 -> bf16 (matches v_cvt semantics)
__device__ __forceinline__ u16 bf16rne(float f) {
    unsigned u = __float_as_uint(f);
    return (u16)((u + 0x7FFFu + ((u >> 16) & 1u)) >> 16);
}
__device__ __forceinline__ float b2f(u16 h) {
    return __uint_as_float(((unsigned)h) << 16);
}

// ---------------------------------------------------------------------------
// fp32 -> bf16 hi/lo conversion (grid-stride, float4 vectorized)
// ---------------------------------------------------------------------------
__global__ __launch_bounds__(256)
void convert_hilo(const float* __restrict__ in, u16* __restrict__ hi,
                  u16* __restrict__ lo, int n4)
{
    for (int i = blockIdx.x * 256 + threadIdx.x; i < n4; i += gridDim.x * 256) {
        float4 v = ((const float4*)in)[i];
        u16 h0 = bf16rne(v.x), h1 = bf16rne(v.y), h2 = bf16rne(v.z), h3 = bf16rne(v.w);
        uint2 hp;
        hp.x = (unsigned)h0 | ((unsigned)h1 << 16);
        hp.y = (unsigned)h2 | ((unsigned)h3 << 16);
        ((uint2*)hi)[i] = hp;
        u16 l0 = bf16rne(v.x - b2f(h0)), l1 = bf16rne(v.y - b2f(h1));
        u16 l2 = bf16rne(v.z - b2f(h2)), l3 = bf16rne(v.w - b2f(h3));
        uint2 lp;
        lp.x = (unsigned)l0 | ((unsigned)l1 << 16);
        lp.y = (unsigned)l2 | ((unsigned)l3 << 16);
        ((uint2*)lo)[i] = lp;
    }
}

// ---------------------------------------------------------------------------
// fp32 [rows][cols] -> bf16 hi/lo transposed [cols][rows]   (for U^T)
// ---------------------------------------------------------------------------
__global__ __launch_bounds__(256)
void transpose_f32_hilo(const float* __restrict__ in, u16* __restrict__ oh,
                        u16* __restrict__ ol, int rows, int cols)
{
    __shared__ float t[32][33];
    const int tx = threadIdx.x & 31, ty = threadIdx.x >> 5;
    const int r0 = blockIdx.y * 32, c0 = blockIdx.x * 32;
    #pragma unroll
    for (int i = 0; i < 4; i++)
        t[ty + i * 8][tx] = in[(size_t)(r0 + ty + i * 8) * cols + c0 + tx];
    __syncthreads();
    #pragma unroll
    for (int i = 0; i < 4; i++) {
        float v = t[tx][ty + i * 8];
        u16 h = bf16rne(v);
        size_t o = (size_t)(c0 + ty + i * 8) * rows + r0 + tx;
        oh[o] = h;
        ol[o] = bf16rne(v - b2f(h));
    }
}

// ---------------------------------------------------------------------------
// V [L,B,E] bf16 -> Vt [B*H, D, L] bf16 (per-head transpose so PV is TRANSB)
// ---------------------------------------------------------------------------
__global__ __launch_bounds__(256)
void transpose_v_bf16(const u16* __restrict__ vh, u16* __restrict__ vt)
{
    __shared__ u16 t[32][34];
    const int tx = threadIdx.x & 31, ty = threadIdx.x >> 5;
    const int l0 = blockIdx.x * 32, d0 = blockIdx.y * 32;
    const int z = blockIdx.z, b = z >> 4, h = z & 15;
    #pragma unroll
    for (int i = 0; i < 4; i++)
        t[ty + i * 8][tx] =
            vh[(size_t)((l0 + ty + i * 8) * B_SZ + b) * E_DIM + h * D_HEAD + d0 + tx];
    __syncthreads();
    #pragma unroll
    for (int i = 0; i < 4; i++)
        vt[(size_t)(z * D_HEAD + d0 + ty + i * 8) * L_SEQ + l0 + tx] = t[tx][ty + i * 8];
}

// ---------------------------------------------------------------------------
// mask zero-detection: fast path flag for attn_fused
// ---------------------------------------------------------------------------
__global__ void flag_init(int* f) { if (threadIdx.x == 0) *f = 0; }

__global__ __launch_bounds__(256)
void mask_scan(const float* __restrict__ m, int* __restrict__ f, int n4)
{
    int nz = 0;
    for (int i = blockIdx.x * 256 + threadIdx.x; i < n4; i += gridDim.x * 256) {
        float4 v = ((const float4*)m)[i];
        nz |= (v.x != 0.0f) | (v.y != 0.0f) | (v.z != 0.0f) | (v.w != 0.0f);
    }
    if (nz) atomicOr(f, 1);
}

// ---------------------------------------------------------------------------
// MFMA GEMM:  C = alpha * A @ B^T + beta * Cin + bias   (verified round 1)
// ---------------------------------------------------------------------------
template <int BN, bool SPLIT, bool AF32>
__global__ __launch_bounds__(256)
void gemm_mfma(const void* __restrict__ Ah_, const void* __restrict__ Al_,
               const u16* __restrict__ Bh_, const u16* __restrict__ Bl_,
               float* __restrict__ Cf, u16* __restrict__ Ch, u16* __restrict__ Cl,
               const u16* __restrict__ Cinh, const u16* __restrict__ Cinl,
               const float* __restrict__ bias,
               int M, int N, int K, int lda, int ldb, int ldc,
               long aStride, int aMode, long bStride, int bMode,
               long cStride, int cMode, float alpha, float beta)
{
    constexpr int BM = 128, BK = 64;
    constexpr int WN = BN / 32;
    constexpr int ALO = BM * BK, BLO = BN * BK;
    __shared__ __align__(16) u16 As[(SPLIT ? 2 : 1) * BM * BK];
    __shared__ __align__(16) u16 Bs[(SPLIT ? 2 : 1) * BN * BK];

    const int tid = threadIdx.x;
    const int z = blockIdx.z;
    const int headOff = (z >> 4) * E_DIM + (z & 15) * D_HEAD;
    const int aOff = aMode ? headOff : (int)(z * aStride);
    const int bOff = bMode ? headOff : (int)(z * bStride);
    const int cOff = cMode ? headOff : (int)(z * cStride);
    const int tm = blockIdx.y * BM, tn = blockIdx.x * BN;

    const int sRow = tid >> 3, sG = tid & 7;
    const int lane = tid & 63;
    const int fr = lane & 15, kg = lane >> 4;
    const int wave = tid >> 6;
    const int wm = (wave >> 1) * 64;
    const int wn = (wave & 1) * (BN / 2);

    f32x4 acc[4][WN] = {};

    for (int k0 = 0; k0 < K; k0 += BK) {
        if constexpr (!AF32) {
            const u16* Ah = (const u16*)Ah_ + aOff + k0;
            #pragma unroll
            for (int i = 0; i < 4; i++) {
                int row = sRow + i * 32;
                int p = sG ^ (row & 7);
                int dst = row * BK + p * 8;
                *(uint4*)&As[dst] = *(const uint4*)(Ah + (tm + row) * lda + sG * 8);
                if constexpr (SPLIT) {
                    const u16* Al = (const u16*)Al_ + aOff + k0;
                    *(uint4*)&As[ALO + dst] = *(const uint4*)(Al + (tm + row) * lda + sG * 8);
                }
            }
        } else {
            const float* Af = (const float*)Ah_ + aOff + k0;
            const int rowF = tid >> 4, qF = tid & 15;
            #pragma unroll
            for (int i = 0; i < 8; i++) {
                int row = rowF + i * 16;
                float4 v = *(const float4*)(Af + (long)(tm + row) * lda + qF * 4);
                int p = (qF >> 1) ^ (row & 7);
                uint2 pk;
                pk.x = (unsigned)bf16rne(v.x) | ((unsigned)bf16rne(v.y) << 16);
                pk.y = (unsigned)bf16rne(v.z) | ((unsigned)bf16rne(v.w) << 16);
                *(uint2*)&As[row * BK + p * 8 + (qF & 1) * 4] = pk;
            }
        }
        {
            const u16* Bh = Bh_ + bOff + k0;
            #pragma unroll
            for (int i = 0; i < BN / 32; i++) {
                int row = sRow + i * 32;
                int p = sG ^ (row & 7);
                int dst = row * BK + p * 8;
                *(uint4*)&Bs[dst] = *(const uint4*)(Bh + (tn + row) * ldb + sG * 8);
                if constexpr (SPLIT) {
                    const u16* Bl = Bl_ + bOff + k0;
                    *(uint4*)&Bs[BLO + dst] = *(const uint4*)(Bl + (tn + row) * ldb + sG * 8);
                }
            }
        }
        __syncthreads();

        #pragma unroll
        for (int ks = 0; ks < 2; ks++) {
            bf16x8 ah[4], al[4];
            #pragma unroll
            for (int m = 0; m < 4; m++) {
                int row = wm + m * 16 + fr;
                int p = (ks * 4 + kg) ^ (row & 7);
                ah[m] = *(const bf16x8*)&As[row * BK + p * 8];
                if constexpr (SPLIT)
                    al[m] = *(const bf16x8*)&As[ALO + row * BK + p * 8];
            }
            #pragma unroll
            for (int n = 0; n < WN; n++) {
                int col = wn + n * 16 + fr;
                int p = (ks * 4 + kg) ^ (col & 7);
                bf16x8 bh = *(const bf16x8*)&Bs[col * BK + p * 8];
                #pragma unroll
                for (int m = 0; m < 4; m++)
                    acc[m][n] = __builtin_amdgcn_mfma_f32_16x16x32_bf16(ah[m], bh, acc[m][n], 0, 0, 0);
                if constexpr (SPLIT) {
                    bf16x8 bl = *(const bf16x8*)&Bs[BLO + col * BK + p * 8];
                    #pragma unroll
                    for (int m = 0; m < 4; m++) {
                        acc[m][n] = __builtin_amdgcn_mfma_f32_16x16x32_bf16(al[m], bh, acc[m][n], 0, 0, 0);
                        acc[m][n] = __builtin_amdgcn_mfma_f32_16x16x32_bf16(ah[m], bl, acc[m][n], 0, 0, 0);
                    }
                }
            }
        }
        __syncthreads();
    }

    #pragma unroll
    for (int m = 0; m < 4; m++) {
        int row0 = tm + wm + m * 16 + kg * 4;
        #pragma unroll
        for (int n = 0; n < WN; n++) {
            int col = tn + wn + n * 16 + fr;
            float bv = bias ? bias[col] : 0.0f;
            #pragma unroll
            for (int j = 0; j < 4; j++) {
                int idx = cOff + (row0 + j) * ldc + col;
                float v = alpha * acc[m][n][j] + bv;
                if (beta != 0.0f) {
                    float ci = b2f(Cinh[idx]);
                    if (Cinl) ci += b2f(Cinl[idx]);
                    v += beta * ci;
                }
                if (Cf) Cf[idx] = v;
                if (Ch) {
                    u16 h = bf16rne(v);
                    Ch[idx] = h;
                    if (Cl) Cl[idx] = bf16rne(v - b2f(h));
                }
            }
        }
    }
}

// ---------------------------------------------------------------------------
// Fused attention: scores (QK^T/8 + mask) -> exact 2-pass softmax -> attn
// weights (fp32 out) + PV context (bf16 hi/lo out). Per block: 64 q-rows of
// one (b,h); 4 waves, each owning 16 complete q-rows (1 m-frag x 4 n-frags).
// ---------------------------------------------------------------------------
__global__ __launch_bounds__(256)
void attn_fused(const u16* __restrict__ Qc, const u16* __restrict__ Kc,
                const u16* __restrict__ Vt, float* __restrict__ attn,
                u16* __restrict__ ctxh, u16* __restrict__ ctxl,
                const float* __restrict__ mask, const int* __restrict__ maskFlag)
{
    __shared__ __align__(16) u16 Qs[64 * 64];   // [q][k]  swizzled, 8 KB
    __shared__ __align__(16) u16 Ks[64 * 64];   // [kv][k] swizzled, 8 KB
    __shared__ __align__(16) u16 Vs[64 * 64];   // [d][kv] swizzled, 8 KB
    __shared__ __align__(16) u16 Ps[4][16 * 64];// per-wave [q][kv] swizzled, 8 KB

    const int tid = threadIdx.x;
    const int z  = blockIdx.y;                 // b*16 + h
    const int q0 = blockIdx.x * 64;
    const int qkOff = (z >> 4) * E_DIM + (z & 15) * D_HEAD;  // into [L,B,E] rows
    const long vtOff = (long)z * D_HEAD * L_SEQ;
    const long aOff  = (long)z * L_SEQ * L_SEQ;
    const int ldq = B_SZ * E_DIM;              // 2048

    const int lane = tid & 63;
    const int fr = lane & 15, kg = lane >> 4;
    const int wave = tid >> 6;
    const int wq = wave * 16;                  // wave's q-row base within tile

    const bool useMask = maskFlag[0] != 0;
    const int sR = tid >> 3, sG = tid & 7;     // staging: 32 rows x 8 granules / iter

    // ---- stage Q tile [64 rows][64 k] ----
    #pragma unroll
    for (int i = 0; i < 2; i++) {
        int row = sR + i * 32;
        *(uint4*)&Qs[row * 64 + (sG ^ (row & 7)) * 8] =
            *(const uint4*)(Qc + (long)(q0 + row) * ldq + qkOff + sG * 8);
    }
    __syncthreads();
    bf16x8 qf[2];
    #pragma unroll
    for (int ks = 0; ks < 2; ks++) {
        int row = wq + fr;
        qf[ks] = *(const bf16x8*)&Qs[row * 64 + ((ks * 4 + kg) ^ (row & 7)) * 8];
    }
    __syncthreads();   // Qs dead

    float mrow[4], lrow[4];
    #pragma unroll
    for (int j = 0; j < 4; j++) { mrow[j] = -3.4e38f; lrow[j] = 0.0f; }

    // ================= pass 1: row max & sum =================
    for (int kt = 0; kt < L_SEQ / 64; kt++) {
        const int kv0 = kt * 64;
        #pragma unroll
        for (int i = 0; i < 2; i++) {
            int row = sR + i * 32;
            *(uint4*)&Ks[row * 64 + (sG ^ (row & 7)) * 8] =
                *(const uint4*)(Kc + (long)(kv0 + row) * ldq + qkOff + sG * 8);
        }
        __syncthreads();

        f32x4 acc[4] = {};
        #pragma unroll
        for (int ks = 0; ks < 2; ks++) {
            #pragma unroll
            for (int n = 0; n < 4; n++) {
                int col = n * 16 + fr;
                bf16x8 bh = *(const bf16x8*)&Ks[col * 64 + ((ks * 4 + kg) ^ (col & 7)) * 8];
                acc[n] = __builtin_amdgcn_mfma_f32_16x16x32_bf16(qf[ks], bh, acc[n], 0, 0, 0);
            }
        }
        __syncthreads();   // Ks consumed before restage

        #pragma unroll
        for (int j = 0; j < 4; j++) {
            float v[4];
            #pragma unroll
            for (int n = 0; n < 4; n++) {
                v[n] = acc[n][j] * 0.125f;
                if (useMask)
                    v[n] += mask[(size_t)(q0 + wq + kg * 4 + j) * L_SEQ + kv0 + n * 16 + fr];
            }
            float t0 = fmaxf(fmaxf(v[0], v[1]), fmaxf(v[2], v[3]));
            float nm = fmaxf(mrow[j], t0);
            float sc = __expf(mrow[j] - nm);
            float s  = __expf(v[0] - nm) + __expf(v[1] - nm)
                     + __expf(v[2] - nm) + __expf(v[3] - nm);
            lrow[j] = lrow[j] * sc + s;
            mrow[j] = nm;
        }
    }

    // merge (m,l) across the 16-lane fr-group (cols fully covered per wave)
    #pragma unroll
    for (int j = 0; j < 4; j++) {
        float m_ = mrow[j], l_ = lrow[j];
        #pragma unroll
        for (int off = 1; off < 16; off <<= 1) {
            float mo = __shfl_xor(m_, off, 64);
            float lo2 = __shfl_xor(l_, off, 64);
            float M = fmaxf(m_, mo);
            l_ = l_ * __expf(m_ - M) + lo2 * __expf(mo - M);
            m_ = M;
        }
        mrow[j] = m_;
        lrow[j] = 1.0f / l_;
    }

    // ================= pass 2: normalized attn write + PV =================
    u16* Pw = &Ps[wave][0];
    f32x4 acc_o[4] = {};

    for (int kt = 0; kt < L_SEQ / 64; kt++) {
        const int kv0 = kt * 64;
        #pragma unroll
        for (int i = 0; i < 2; i++) {
            int row = sR + i * 32;
            *(uint4*)&Ks[row * 64 + (sG ^ (row & 7)) * 8] =
                *(const uint4*)(Kc + (long)(kv0 + row) * ldq + qkOff + sG * 8);
            *(uint4*)&Vs[row * 64 + (sG ^ (row & 7)) * 8] =
                *(const uint4*)(Vt + vtOff + (long)row * L_SEQ + kv0 + sG * 8);
        }
        __syncthreads();

        f32x4 acc[4] = {};
        #pragma unroll
        for (int ks = 0; ks < 2; ks++) {
            #pragma unroll
            for (int n = 0; n < 4; n++) {
                int col = n * 16 + fr;
                bf16x8 bh = *(const bf16x8*)&Ks[col * 64 + ((ks * 4 + kg) ^ (col & 7)) * 8];
                acc[n] = __builtin_amdgcn_mfma_f32_16x16x32_bf16(qf[ks], bh, acc[n], 0, 0, 0);
            }
        }

        // P = exp(s - m) / l : write fp32 attn + bf16 into wave-private LDS
        #pragma unroll
        for (int n = 0; n < 4; n++) {
            #pragma unroll
            for (int j = 0; j < 4; j++) {
                int row = kg * 4 + j;          // within wave's 16 rows
                int col = n * 16 + fr;
                float v = acc[n][j] * 0.125f;
                if (useMask)
                    v += mask[(size_t)(q0 + wq + row) * L_SEQ + kv0 + col];
                float p = __expf(v - mrow[j]) * lrow[j];
                attn[aOff + (size_t)(q0 + wq + row) * L_SEQ + kv0 + col] = p;
                Pw[row * 64 + ((col >> 3) ^ (row & 7)) * 8 + (col & 7)] = bf16rne(p);
            }
        }

        // pin order: Pw lane-scatter writes must precede same-wave Pw reads
        // (DS ops execute in program order per wave; this blocks compiler
        //  reordering of the ds_read above the ds_writes — rule #18 class)
        asm volatile("" ::: "memory");

        // PV: O[16 q][64 d] += P[16 q][64 kv] @ Vt[64 d][64 kv]^T
        #pragma unroll
        for (int ks = 0; ks < 2; ks++) {
            int rowA = fr;
            bf16x8 pa = *(const bf16x8*)&Pw[rowA * 64 + ((ks * 4 + kg) ^ (rowA & 7)) * 8];
            #pragma unroll
            for (int n = 0; n < 4; n++) {
                int d = n * 16 + fr;
                bf16x8 vb = *(const bf16x8*)&Vs[d * 64 + ((ks * 4 + kg) ^ (d & 7)) * 8];
                acc_o[n] = __builtin_amdgcn_mfma_f32_16x16x32_bf16(pa, vb, acc_o[n], 0, 0, 0);
            }
        }
        __syncthreads();   // Ks/Vs consumed before restage
    }

    // ---- epilogue: ctx bf16 hi/lo, head-sliced [L,B,E] ----
    #pragma unroll
    for (int n = 0; n < 4; n++) {
        #pragma unroll
        for (int j = 0; j < 4; j++) {
            int row = q0 + wq + kg * 4 + j;
            int d = n * 16 + fr;
            float v = acc_o[n][j];
            size_t idx = (size_t)row * ldq + qkOff + d;
            u16 h = bf16rne(v);
            ctxh[idx] = h;
            ctxl[idx] = bf16rne(v - b2f(h));
        }
    }
}

// ---------------------------------------------------------------------------
extern "C" void kernel_launch(void* const* d_in, const int* in_sizes, int n_in,
                              void* d_out, int out_size, void* d_ws, size_t ws_size,
                              hipStream_t stream)
{
    const float* x    = (const float*)d_in[0];
    const float* mask = (const float*)d_in[1];
    const float* Wq   = (const float*)d_in[2];
    const float* bq   = (const float*)d_in[3];
    const float* Wk   = (const float*)d_in[4];
    const float* bk   = (const float*)d_in[5];
    const float* Wv   = (const float*)d_in[6];
    const float* bv   = (const float*)d_in[7];
    const float* Wo   = (const float*)d_in[8];
    const float* bo   = (const float*)d_in[9];
    const float* U    = (const float*)d_in[10];

    float* out   = (float*)d_out;                               // [L,B,E]
    float* attnF = out + (size_t)L_SEQ * B_SZ * E_DIM;          // [B,H,L,L]

    const int SZ  = L_SEQ * B_SZ * E_DIM;   // 4,194,304
    const int WSZ = E_DIM * E_DIM;          // 1,048,576
    const int USZ = E_DIM * R_DIM;          //   262,144
    const int PSZ = L_SEQ * B_SZ * R_DIM;   // 1,048,576

    // ---- persistent ws (live after attn region is overwritten): 44 MB ----
    u16* Qch  = (u16*)d_ws;
    u16* Kch  = Qch + SZ;
    u16* Vth  = Kch + SZ;          // V^T per head: [B*H, D, L]
    u16* ctxh = Vth + SZ;
    u16* ctxl = ctxh + SZ;
    u16* Woh  = ctxl + SZ;
    u16* Wol  = Woh + WSZ;
    int* maskFlag = (int*)(Wol + WSZ);

    // ---- pre-scores scratch lives in the (not-yet-written) attn region ----
    u16* sc  = (u16*)attnF;
    u16* xh  = sc;          u16* xl  = xh + SZ;
    u16* Qh  = xl + SZ;     u16* Ql  = Qh + SZ;
    u16* Kh  = Ql + SZ;     u16* Kl  = Kh + SZ;
    u16* Vh  = Kl + SZ;
    u16* Wqh = Vh + SZ;     u16* Wql = Wqh + WSZ;
    u16* Wkh = Wql + WSZ;   u16* Wkl = Wkh + WSZ;
    u16* Wvh = Wkl + WSZ;   u16* Wvl = Wvh + WSZ;
    u16* Uh  = Wvl + WSZ;   u16* Ul  = Uh + USZ;
    u16* Uth = Ul + USZ;    u16* Utl = Uth + USZ;   // U^T [R,E]
    u16* Ph  = Utl + USZ;   u16* Pl  = Ph + PSZ;    // ~78 MB << 536 MB

    const dim3 blk(256);
    const int M = L_SEQ * B_SZ;  // 4096

    // 0a. mask zero-detection flag
    hipLaunchKernelGGL(flag_init, dim3(1), dim3(64), 0, stream, maskFlag);
    hipLaunchKernelGGL(mask_scan, dim3(512), blk, 0, stream,
                       mask, maskFlag, (L_SEQ * L_SEQ) / 4);

    // 0b. fp32 -> bf16 hi/lo conversions
    hipLaunchKernelGGL(convert_hilo, dim3(2048), blk, 0, stream, x,  xh,  xl,  SZ / 4);
    hipLaunchKernelGGL(convert_hilo, dim3(512),  blk, 0, stream, Wq, Wqh, Wql, WSZ / 4);
    hipLaunchKernelGGL(convert_hilo, dim3(512),  blk, 0, stream, Wk, Wkh, Wkl, WSZ / 4);
    hipLaunchKernelGGL(convert_hilo, dim3(512),  blk, 0, stream, Wv, Wvh, Wvl, WSZ / 4);
    hipLaunchKernelGGL(convert_hilo, dim3(512),  blk, 0, stream, Wo, Woh, Wol, WSZ / 4);
    hipLaunchKernelGGL(convert_hilo, dim3(128),  blk, 0, stream, U,  Uh,  Ul,  USZ / 4);
    hipLaunchKernelGGL(transpose_f32_hilo, dim3(R_DIM / 32, E_DIM / 32), blk, 0, stream,
                       U, Uth, Utl, E_DIM, R_DIM);

    // 1-3. Q/K/V projections (split-bf16): [4096,1024]
    {
        dim3 g(E_DIM / 128, M / 128, 1);
        hipLaunchKernelGGL((gemm_mfma<128, true, false>), g, blk, 0, stream,
            xh, xl, Wqh, Wql, nullptr, Qh, Ql, nullptr, nullptr, bq,
            M, E_DIM, E_DIM, E_DIM, E_DIM, E_DIM,
            0L, 0, 0L, 0, 0L, 0, 1.0f, 0.0f);
        hipLaunchKernelGGL((gemm_mfma<128, true, false>), g, blk, 0, stream,
            xh, xl, Wkh, Wkl, nullptr, Kh, Kl, nullptr, nullptr, bk,
            M, E_DIM, E_DIM, E_DIM, E_DIM, E_DIM,
            0L, 0, 0L, 0, 0L, 0, 1.0f, 0.0f);
        hipLaunchKernelGGL((gemm_mfma<128, true, false>), g, blk, 0, stream,
            xh, xl, Wvh, Wvl, nullptr, Vh, nullptr, nullptr, nullptr, bv,
            M, E_DIM, E_DIM, E_DIM, E_DIM, E_DIM,
            0L, 0, 0L, 0, 0L, 0, 1.0f, 0.0f);
    }
    hipLaunchKernelGGL(transpose_v_bf16, dim3(L_SEQ / 32, D_HEAD / 32, B_SZ * H_N),
                       blk, 0, stream, Vh, Vth);

    // 4-5. Conditioning: P = Q@U ; Qc = 0.4*P@U^T + 0.6*Q
    {
        dim3 gp(R_DIM / 128, M / 128, 1);
        dim3 gc(E_DIM / 128, M / 128, 1);
        hipLaunchKernelGGL((gemm_mfma<128, true, false>), gp, blk, 0, stream,
            Qh, Ql, Uth, Utl, nullptr, Ph, Pl, nullptr, nullptr, nullptr,
            M, R_DIM, E_DIM, E_DIM, E_DIM, R_DIM,
            0L, 0, 0L, 0, 0L, 0, 1.0f, 0.0f);
        hipLaunchKernelGGL((gemm_mfma<128, true, false>), gc, blk, 0, stream,
            Ph, Pl, Uh, Ul, nullptr, Qch, nullptr, Qh, Ql, nullptr,
            M, E_DIM, R_DIM, R_DIM, R_DIM, E_DIM,
            0L, 0, 0L, 0, 0L, 0, 0.4f, 0.6f);
        hipLaunchKernelGGL((gemm_mfma<128, true, false>), gp, blk, 0, stream,
            Kh, Kl, Uth, Utl, nullptr, Ph, Pl, nullptr, nullptr, nullptr,
            M, R_DIM, E_DIM, E_DIM, E_DIM, R_DIM,
            0L, 0, 0L, 0, 0L, 0, 1.0f, 0.0f);
        hipLaunchKernelGGL((gemm_mfma<128, true, false>), gc, blk, 0, stream,
            Ph, Pl, Uh, Ul, nullptr, Kch, nullptr, Kh, Kl, nullptr,
            M, E_DIM, R_DIM, R_DIM, R_DIM, E_DIM,
            0L, 0, 0L, 0, 0L, 0, 0.4f, 0.6f);
    }

    // 7-9. Fused: scores -> softmax -> attn weights (fp32) + ctx (bf16 hi/lo)
    hipLaunchKernelGGL(attn_fused, dim3(L_SEQ / 64, B_SZ * H_N), blk, 0, stream,
                       Qch, Kch, Vth, attnF, ctxh, ctxl, mask, maskFlag);

    // 10. out = ctx @ Wo^T + bo  (split-bf16)
    {
        dim3 g(E_DIM / 128, M / 128, 1);
        hipLaunchKernelGGL((gemm_mfma<128, true, false>), g, blk, 0, stream,
            ctxh, ctxl, Woh, Wol, out, nullptr, nullptr, nullptr, nullptr, bo,
            M, E_DIM, E_DIM, E_DIM, E_DIM, E_DIM,
            0L, 0, 0L, 0, 0L, 0, 1.0f, 0.0f);
    }
}